// Round 1
// baseline (70.782 us; speedup 1.0000x reference)
//
#include <hip/hip_runtime.h>
#include <hip/hip_bf16.h>

namespace {

constexpr int kN = 64;               // rows per (s,p) block
constexpr int kD = 128;              // feature dim
constexpr int kF4 = kD / 4;          // 32 float4 per row
constexpr int kStride = kF4 + 1;     // 33 float4 (132 floats): 132 % 32 == 4 -> 2-way max aliasing
constexpr int kXRows = 16;           // x rows per block (N/4); 4 blocks per (s,p)

__global__ __launch_bounds__(256, 2)
void vcmp_kernel(const float* __restrict__ x, const float* __restrict__ y,
                 float* __restrict__ out) {
  __shared__ float4 xs[kXRows * kStride];   // 16 rows of x, padded
  __shared__ float4 ys[kN * kStride];       // all 64 rows of y, padded
  __shared__ float xn2[kXRows], xrn[kXRows];
  __shared__ float yn2[kN], yrn[kN];

  const int tid = threadIdx.x;
  const int bid = blockIdx.x;
  const int sp  = bid >> 2;            // (s,p) flat index, 0..127
  const int r0  = (bid & 3) * kXRows;  // x-row base within this (s,p)

  // ---- global -> LDS staging (coalesced float4) ----
  const float4* gx = reinterpret_cast<const float4*>(x) + ((size_t)sp * kN + r0) * kF4;
  const float4* gy = reinterpret_cast<const float4*>(y) + (size_t)sp * kN * kF4;

  #pragma unroll
  for (int i = tid; i < kXRows * kF4; i += 256) {           // 2 iters
    xs[(i >> 5) * kStride + (i & 31)] = gx[i];
  }
  #pragma unroll
  for (int i = tid; i < kN * kF4; i += 256) {               // 8 iters
    ys[(i >> 5) * kStride + (i & 31)] = gy[i];
  }
  __syncthreads();

  // ---- per-row squared norms + reciprocal norms (80 rows total) ----
  if (tid < kXRows + kN) {
    const float4* row = (tid < kXRows) ? (xs + tid * kStride)
                                       : (ys + (tid - kXRows) * kStride);
    float s = 0.f;
    #pragma unroll
    for (int c = 0; c < kF4; ++c) {
      const float4 v = row[c];
      s = fmaf(v.x, v.x, s); s = fmaf(v.y, v.y, s);
      s = fmaf(v.z, v.z, s); s = fmaf(v.w, v.w, s);
    }
    const float rn = 1.f / fmaxf(sqrtf(s), 1e-12f);  // matches normalize eps
    if (tid < kXRows) { xn2[tid] = s; xrn[tid] = rn; }
    else              { yn2[tid - kXRows] = s; yrn[tid - kXRows] = rn; }
  }
  __syncthreads();

  // ---- main: thread (tn, tm) handles n = r0+tn, m = tm + 16j (j=0..3) ----
  const int tn = tid >> 4;   // 0..15
  const int tm = tid & 15;   // 0..15

  float dot[4] = {0.f, 0.f, 0.f, 0.f};
  float l1 [4] = {0.f, 0.f, 0.f, 0.f};
  const float4* xrow = xs + tn * kStride;

  #pragma unroll 4
  for (int c = 0; c < kF4; ++c) {
    const float4 xv = xrow[c];                       // broadcast across wave
    #pragma unroll
    for (int j = 0; j < 4; ++j) {
      const float4 yv = ys[(tm + 16 * j) * kStride + c];   // 2-way max aliasing
      dot[j] = fmaf(xv.x, yv.x, dot[j]);
      dot[j] = fmaf(xv.y, yv.y, dot[j]);
      dot[j] = fmaf(xv.z, yv.z, dot[j]);
      dot[j] = fmaf(xv.w, yv.w, dot[j]);
      l1[j] += fabsf(xv.x - yv.x);
      l1[j] += fabsf(xv.y - yv.y);
      l1[j] += fabsf(xv.z - yv.z);
      l1[j] += fabsf(xv.w - yv.w);
    }
  }

  // ---- epilogue: cos = dot/(nx*ny), l2 = sqrt(nx^2 + ny^2 - 2 dot) ----
  const float nx2 = xn2[tn];
  const float rnx = xrn[tn];
  float* op = out + (size_t)(sp * kN + r0 + tn) * kN * 3;
  #pragma unroll
  for (int j = 0; j < 4; ++j) {
    const int m = tm + 16 * j;
    const float d2 = fmaxf(nx2 + yn2[m] - 2.f * dot[j], 0.f);
    float3 v;
    v.x = dot[j] * rnx * yrn[m];   // cos
    v.y = sqrtf(d2);               // l2
    v.z = l1[j];                   // l1
    *reinterpret_cast<float3*>(op + (size_t)m * 3) = v;
  }
}

} // namespace

extern "C" void kernel_launch(void* const* d_in, const int* in_sizes, int n_in,
                              void* d_out, int out_size, void* d_ws, size_t ws_size,
                              hipStream_t stream) {
  const float* x = (const float*)d_in[0];
  const float* y = (const float*)d_in[1];
  float* out = (float*)d_out;
  vcmp_kernel<<<dim3(512), dim3(256), 0, stream>>>(x, y, out);
}

// Round 2
// 70.126 us; speedup vs baseline: 1.0094x; 1.0094x over previous
//
#include <hip/hip_runtime.h>
#include <hip/hip_bf16.h>

namespace {

constexpr int kN = 64;               // rows per (s,p) block
constexpr int kF4 = 32;              // 32 float4 per row (D=128)
constexpr int kStride = kF4 + 1;     // 33 float4: 132 floats ≡ 4 mod 32 banks -> ≤2-way aliasing
constexpr int kXRows = 32;           // x rows per block (N/2); 2 blocks per (s,p)

__global__ __launch_bounds__(256, 2)
void vcmp_kernel(const float* __restrict__ x, const float* __restrict__ y,
                 float* __restrict__ out) {
  __shared__ float4 xs[kXRows * kStride];   // 32 rows of x, padded   (16.9 KB)
  __shared__ float4 ys[kN * kStride];       // all 64 rows of y       (33.8 KB)
  __shared__ float xn2[kXRows], xrn[kXRows];
  __shared__ float yn2[kN], yrn[kN];

  const int tid = threadIdx.x;
  const int bid = blockIdx.x;
  const int sp  = bid >> 1;            // (s,p) flat index, 0..127
  const int r0  = (bid & 1) << 5;      // x-row base within this (s,p): 0 or 32

  // ---- global -> LDS staging (coalesced float4) ----
  const float4* gx = reinterpret_cast<const float4*>(x) + ((size_t)sp * kN + r0) * kF4;
  const float4* gy = reinterpret_cast<const float4*>(y) + (size_t)sp * kN * kF4;

  #pragma unroll
  for (int i = tid; i < kXRows * kF4; i += 256) {           // 4 iters
    xs[(i >> 5) * kStride + (i & 31)] = gx[i];
  }
  #pragma unroll
  for (int i = tid; i < kN * kF4; i += 256) {               // 8 iters
    ys[(i >> 5) * kStride + (i & 31)] = gy[i];
  }
  __syncthreads();

  // ---- per-row squared norms + reciprocal norms (96 rows total) ----
  if (tid < kXRows + kN) {
    const float4* row = (tid < kXRows) ? (xs + tid * kStride)
                                       : (ys + (tid - kXRows) * kStride);
    float s = 0.f;
    #pragma unroll
    for (int c = 0; c < kF4; ++c) {
      const float4 v = row[c];
      s = fmaf(v.x, v.x, s); s = fmaf(v.y, v.y, s);
      s = fmaf(v.z, v.z, s); s = fmaf(v.w, v.w, s);
    }
    const float rn = 1.f / fmaxf(sqrtf(s), 1e-12f);  // matches normalize eps
    if (tid < kXRows) { xn2[tid] = s; xrn[tid] = rn; }
    else              { yn2[tid - kXRows] = s; yrn[tid - kXRows] = rn; }
  }
  __syncthreads();

  // ---- main: thread (tn, tm): n = 2*tn + {0,1}, m = tm + 16j (j=0..3) ----
  const int tn = tid >> 4;   // 0..15
  const int tm = tid & 15;   // 0..15
  const int n0 = tn << 1;    // local x row base (pair of rows)

  float dot0[4] = {0.f, 0.f, 0.f, 0.f};
  float dot1[4] = {0.f, 0.f, 0.f, 0.f};
  float l10 [4] = {0.f, 0.f, 0.f, 0.f};
  float l11 [4] = {0.f, 0.f, 0.f, 0.f};
  const float4* xrow0 = xs + n0 * kStride;
  const float4* xrow1 = xrow0 + kStride;

  #pragma unroll 2
  for (int c = 0; c < kF4; ++c) {
    const float4 a0 = xrow0[c];                      // banks 8*tn .. +3 : conflict-free
    const float4 a1 = xrow1[c];
    #pragma unroll
    for (int j = 0; j < 4; ++j) {
      const float4 b = ys[(tm + 16 * j) * kStride + c];   // ≤2-way aliasing (free)
      dot0[j] = fmaf(a0.x, b.x, dot0[j]);
      dot0[j] = fmaf(a0.y, b.y, dot0[j]);
      dot0[j] = fmaf(a0.z, b.z, dot0[j]);
      dot0[j] = fmaf(a0.w, b.w, dot0[j]);
      dot1[j] = fmaf(a1.x, b.x, dot1[j]);
      dot1[j] = fmaf(a1.y, b.y, dot1[j]);
      dot1[j] = fmaf(a1.z, b.z, dot1[j]);
      dot1[j] = fmaf(a1.w, b.w, dot1[j]);
      l10[j] += fabsf(a0.x - b.x);
      l10[j] += fabsf(a0.y - b.y);
      l10[j] += fabsf(a0.z - b.z);
      l10[j] += fabsf(a0.w - b.w);
      l11[j] += fabsf(a1.x - b.x);
      l11[j] += fabsf(a1.y - b.y);
      l11[j] += fabsf(a1.z - b.z);
      l11[j] += fabsf(a1.w - b.w);
    }
  }

  // ---- epilogue: cos = dot/(nx*ny), l2 = sqrt(nx^2 + ny^2 - 2 dot) ----
  #pragma unroll
  for (int r = 0; r < 2; ++r) {
    const int nl = n0 + r;               // local row 0..31
    const float nx2 = xn2[nl];
    const float rnx = xrn[nl];
    const float* dt = r ? dot1 : dot0;
    const float* lo = r ? l11  : l10;
    float* op = out + (size_t)(sp * kN + r0 + nl) * kN * 3;
    #pragma unroll
    for (int j = 0; j < 4; ++j) {
      const int m = tm + 16 * j;
      const float d2 = fmaxf(nx2 + yn2[m] - 2.f * dt[j], 0.f);
      float3 v;
      v.x = dt[j] * rnx * yrn[m];   // cos
      v.y = sqrtf(d2);              // l2
      v.z = lo[j];                  // l1
      *reinterpret_cast<float3*>(op + (size_t)m * 3) = v;
    }
  }
}

} // namespace

extern "C" void kernel_launch(void* const* d_in, const int* in_sizes, int n_in,
                              void* d_out, int out_size, void* d_ws, size_t ws_size,
                              hipStream_t stream) {
  const float* x = (const float*)d_in[0];
  const float* y = (const float*)d_in[1];
  float* out = (float*)d_out;
  vcmp_kernel<<<dim3(256), dim3(256), 0, stream>>>(x, y, out);
}